// Round 1
// baseline (621.307 us; speedup 1.0000x reference)
//
#include <hip/hip_runtime.h>

// Problem constants (from reference setup_inputs)
#define T_STEPS 15
#define CIN     64
#define H_IN    256
#define W_IN    256
#define COUT    128
#define HO      252
#define WO      252
#define KWIN    16
#define KH      5
#define KW      5
#define LOWERB  0.0f
#define UPPERB  1.0f

#define W_ELEMS (COUT * CIN * KH * KW)   // 204800

__global__ __launch_bounds__(256) void stdp_update_kernel(
    const float* __restrict__ in_spikes,   // (T, Cin, H, W)
    const float* __restrict__ out_spikes,  // (T, Cout, Ho, Wo)
    const int*   __restrict__ winners,     // (K, 3) int32: f, r, c
    const float* __restrict__ weight,      // (Cout, Cin, KH, KW)
    const float* __restrict__ ltp,         // (Cout,)
    const float* __restrict__ ltd,         // (Cout,)
    float*       __restrict__ out)         // (Cout, Cin, KH, KW)
{
    __shared__ int   wf[KWIN];
    __shared__ int   wr[KWIN];
    __shared__ int   wc[KWIN];
    __shared__ float wol[KWIN];  // out_lat at each winner position

    const int tid = threadIdx.x;
    if (tid < KWIN) {
        const int f = winners[3 * tid + 0];
        const int r = winners[3 * tid + 1];
        const int c = winners[3 * tid + 2];
        wf[tid] = f; wr[tid] = r; wc[tid] = c;
        // out_lat[f, r, c] = sum_t output_spikes[t, f, r, c]
        // 240 distinct addresses chip-wide -> L2 broadcast across blocks.
        size_t base = (size_t)f * (HO * WO) + (size_t)r * WO + (size_t)c;
        float s = 0.0f;
        #pragma unroll
        for (int t = 0; t < T_STEPS; ++t)
            s += out_spikes[base + (size_t)t * (COUT * HO * WO)];
        wol[tid] = s;
    }
    __syncthreads();

    const int idx = blockIdx.x * blockDim.x + tid;
    if (idx >= W_ELEMS) return;

    const int cout = idx / (CIN * KH * KW);
    const int rem  = idx % (CIN * KH * KW);

    // Is this output channel a winner? (winner channels are distinct)
    int k = -1;
    #pragma unroll
    for (int i = 0; i < KWIN; ++i)
        if (wf[i] == cout) k = i;

    const float w = weight[idx];
    float nw;
    if (k < 0) {
        nw = w;  // lr == 0 -> just clip
    } else {
        const int cin = rem / (KH * KW);
        const int p   = rem % (KH * KW);
        const int kh  = p / KW;
        const int kw  = p % KW;
        const int r   = wr[k] + kh;   // r in [0,252) so r+kh <= 256 : in bounds
        const int c   = wc[k] + kw;
        // in_lat[cin, r, c] = sum_t input_spikes[t, cin, r, c]
        size_t base = (size_t)cin * (H_IN * W_IN) + (size_t)r * W_IN + (size_t)c;
        float s = 0.0f;
        #pragma unroll
        for (int t = 0; t < T_STEPS; ++t)
            s += in_spikes[base + (size_t)t * (CIN * H_IN * W_IN)];
        const float lr = (s >= wol[k]) ? ltp[cout] : ltd[cout];
        nw = w + lr * ((w - LOWERB) * (UPPERB - w));
    }
    nw = fminf(fmaxf(nw, LOWERB), UPPERB);
    out[idx] = nw;
}

extern "C" void kernel_launch(void* const* d_in, const int* in_sizes, int n_in,
                              void* d_out, int out_size, void* d_ws, size_t ws_size,
                              hipStream_t stream) {
    const float* in_spikes  = (const float*)d_in[0];
    const float* out_spikes = (const float*)d_in[1];
    const int*   winners    = (const int*)d_in[2];
    const float* weight     = (const float*)d_in[3];
    const float* ltp        = (const float*)d_in[4];
    const float* ltd        = (const float*)d_in[5];
    float*       out        = (float*)d_out;

    const int block = 256;
    const int grid  = (W_ELEMS + block - 1) / block;  // 800 blocks
    stdp_update_kernel<<<grid, block, 0, stream>>>(
        in_spikes, out_spikes, winners, weight, ltp, ltd, out);
}